// Round 1
// 318.424 us; speedup vs baseline: 1.0050x; 1.0050x over previous
//
#include <hip/hip_runtime.h>

// PNN fused, round 6: FULL single-kernel fusion.
//
// Rationale (from rocprof): top dispatches are the harness's ~1 GB workspace
// poison fills (149 us each, fixed). Our kernels are < 148 us each; the
// removable waste is the 21 MB Aws write + 21 MB read round-trip, the LDS->
// global flush, and one kernel launch. The random gather (639K x 64B lines,
// L3 cold each iteration because the poison fill wipes it) stays as-is --
// identical 4-lane/line de-diverged pattern, identical in-flight load count
// (2 blocks/CU x 8 waves x 10 loads = 160 VMEM instrs/CU, same as round 5's
// 4 x 4 x 10).
//
// One block = 32 rows end-to-end:
//   1. stage Xi/Xv (312 int4/float4 loads),
//   2. gather 32x39x4 = 4992 16B chunks into LDS A-fragments (verified slot
//      formula, now 2 rowtiles), table loads nontemporal,
//   3. K-loop: A from LDS (ds_read_b128, conflict-free), B converted
//      in-register from fp32 w_first/w_inner (2 x float4 per lane per step;
//      per wave per step = 16 rows x 128 B contiguous, L2-hot after first
//      blocks -- weights are only 160 KB). t=19/kq>=2 zeroed (K pad 624->640).
//   4. verified fused fp32 MLP, scratch union-aliased over the A-tile LDS
//      behind an extra barrier.
// Workspace entirely unused. LDS = 51 KB -> 2 blocks/CU resident (grid 512),
// __launch_bounds__(512,4) caps VGPR at 128 to guarantee it.

namespace {

typedef _Float16 half8 __attribute__((ext_vector_type(8)));
typedef _Float16 half4 __attribute__((ext_vector_type(4)));
typedef float floatx4 __attribute__((ext_vector_type(4)));
typedef float f32x4 __attribute__((ext_vector_type(4)));

constexpr int Bn = 16384;
constexpr int Fn = 39;
constexpr int Vn = 100000;
constexpr int En = 16;
constexpr int M = 32;                 // rows per block
constexpr int KST = 20;               // k-steps of 32 (624 padded to 640)
constexpr int GITER = 10;             // ceil(4992 / 512) gather chunk-iters

__device__ __forceinline__ half8 cvt8(float4 a, float4 b) {
    half8 h;
    h[0] = (_Float16)a.x; h[1] = (_Float16)a.y;
    h[2] = (_Float16)a.z; h[3] = (_Float16)a.w;
    h[4] = (_Float16)b.x; h[5] = (_Float16)b.y;
    h[6] = (_Float16)b.z; h[7] = (_Float16)b.w;
    return h;
}

__device__ __forceinline__ half4 cvt4s(f32x4 a, float s) {
    half4 h;
    h[0] = (_Float16)(a[0] * s);
    h[1] = (_Float16)(a[1] * s);
    h[2] = (_Float16)(a[2] * s);
    h[3] = (_Float16)(a[3] * s);
    return h;
}

struct SMemGather {
    _Float16 At[2][KST * 512];   // 2 rowtiles x 10240 halfs = 40 KB
    int   xi[M * Fn];            // 1248
    float xv[M * Fn];            // 1248
};

struct SMemMlp {
    float x[M * 69];     // x[row][d], stride 69 -> conflict-free
    float wsh[2176];     // lin1_W[0..1023] lin2_W[1024..2047] b1@2048 b2@2080 lastW@2112 lastb@2144
    float r1[1024];
    float r2[1024];
};

union SMemU {
    SMemGather g;        // 50,944 B (live: stage + gather + K-loop)
    SMemMlp m;           // 25,728 B (live: after post-K barrier)
};

__global__ __launch_bounds__(512, 4) void pnn_fused(
    const int* __restrict__ Xi,
    const float* __restrict__ Xv,
    const float* __restrict__ T,
    const float* __restrict__ w_first,
    const float* __restrict__ w_inner,
    const float* __restrict__ lin1_W,
    const float* __restrict__ lin1_b,
    const float* __restrict__ lin2_W,
    const float* __restrict__ lin2_b,
    const float* __restrict__ last_W,
    const float* __restrict__ last_b,
    float* __restrict__ out)
{
    __shared__ SMemU sm;

    const int tid = threadIdx.x;
    const int lane = tid & 63;
    const int wv = tid >> 6;
    const int q = wv & 1;        // row-half (16 rows)
    const int t16 = wv >> 1;     // col-tile (16 cols)
    const int row0 = blockIdx.x * M;

    // ---- stage Xi/Xv coalesced (1248 ints/floats = 312 x 16B each) ----
    if (tid < 312) {
        reinterpret_cast<int4*>(sm.g.xi)[tid] =
            reinterpret_cast<const int4*>(Xi + (size_t)row0 * Fn)[tid];
        reinterpret_cast<float4*>(sm.g.xv)[tid] =
            reinterpret_cast<const float4*>(Xv + (size_t)row0 * Fn)[tid];
    }
    if (tid < 64) {    // zero K-pad: kstep 19, lanes 32..63, both rowtiles
        half8 z = {0, 0, 0, 0, 0, 0, 0, 0};
        const int qq = tid >> 5;
        *reinterpret_cast<half8*>(
            &sm.g.At[qq][((KST - 1) * 64 + 32 + (tid & 31)) * 8]) = z;
    }
    __syncthreads();

    // ---- gather: task i (0..4991): line j=i>>2 (row r=j&31, feat f=j>>5),
    // chunk c=i&3. 4 consecutive lanes share one 64B line -> wave instr
    // touches 16 lines, 4-lane coalesced. All loads issued before any LDS
    // write (batched latency). ----
    f32x4 v[GITER];
    float s[GITER];
    int   slot[GITER];
    bool  ok[GITER];
#pragma unroll
    for (int it = 0; it < GITER; ++it) {
        const int i = tid + it * 512;
        ok[it] = (i < M * Fn * 4);
        if (ok[it]) {
            const int j = i >> 2, c = i & 3;
            const int r = j & 31, f = j >> 5;
            const int idx = sm.g.xi[r * Fn + f];
            s[it] = sm.g.xv[r * Fn + f];
            const f32x4* src = reinterpret_cast<const f32x4*>(
                T + ((size_t)f * Vn + (size_t)idx) * En + c * 4);
            v[it] = __builtin_nontemporal_load(src);
            // A-frag slot (halfs), verified layout, rowtile = r>>4:
            slot[it] = (r >> 4) * (KST * 512)
                     + (((f >> 1) * 64) + (f & 1) * 32 + (r & 15)) * 8
                     + (c >> 1) * 128 + (c & 1) * 4;
        }
    }
#pragma unroll
    for (int it = 0; it < GITER; ++it) {
        if (ok[it])
            *reinterpret_cast<half4*>(&sm.g.At[0][0] + slot[it]) =
                cvt4s(v[it], s[it]);
    }
    __syncthreads();

    // ---- K-loop: A from LDS, B converted in-register from fp32 weights ----
    // lane holds B[col = t16*16 + (lane&15)][k = kq*8 .. kq*8+7] per step.
    const int n = t16 * 16 + (lane & 15);          // 0..63 weight row
    const int kq = lane >> 4;                      // 0..3
    const float* wrow = (n < 32) ? (w_first + (size_t)n * 624)
                                 : (w_inner + (size_t)(n - 32) * 624);
    const _Float16* aLds = &sm.g.At[q][lane * 8];

    floatx4 acc = {0.0f, 0.0f, 0.0f, 0.0f};
#pragma unroll
    for (int t = 0; t < KST; ++t) {
        const half8 af = *reinterpret_cast<const half8*>(aLds + t * 512);
        half8 bf;
        if (t == KST - 1 && kq >= 2) {   // kb >= 624: K pad, avoid OOB/NaN
            bf = half8{0, 0, 0, 0, 0, 0, 0, 0};
        } else {
            const int kb = t * 32 + kq * 8;
            const float4 a = *reinterpret_cast<const float4*>(wrow + kb);
            const float4 b = *reinterpret_cast<const float4*>(wrow + kb + 4);
            bf = cvt8(a, b);
        }
        acc = __builtin_amdgcn_mfma_f32_16x16x32_f16(af, bf, acc, 0, 0, 0);
    }

    // all waves done reading At -> MLP scratch may alias it
    __syncthreads();

    // ---- write C tile: col=lane&15, row=(lane>>4)*4+reg ----
    {
        const int col = t16 * 16 + (lane & 15);
        const int rbase = q * 16 + (lane >> 4) * 4;
#pragma unroll
        for (int r = 0; r < 4; ++r)
            sm.m.x[(rbase + r) * 69 + col] = acc[r];
    }

    // ---- stage MLP weights ----
    for (int i = tid; i < 2145; i += 512) {
        float vv;
        if (i < 1024)      vv = lin1_W[i];
        else if (i < 2048) vv = lin2_W[i - 1024];
        else if (i < 2080) vv = lin1_b[i - 2048];
        else if (i < 2112) vv = lin2_b[i - 2080];
        else if (i < 2144) vv = last_W[i - 2112];
        else               vv = last_b[0];
        sm.m.wsh[i] = vv;
    }
    __syncthreads();

    // ---- xin[j][r] = first + s^2 ----
    for (int p = tid; p < 1024; p += 512) {
        const int j = p >> 5, r = p & 31;
        const float fi = sm.m.x[r * 69 + j];
        const float sq = sm.m.x[r * 69 + 32 + j];
        sm.m.r1[j * 32 + r] = fi + sq * sq;
    }
    __syncthreads();

    // ---- layer 1 ----
    {
        const int r = tid & 31, n0 = (tid >> 5) * 2;
        float a0 = sm.m.wsh[2048 + n0];
        float a1 = sm.m.wsh[2048 + n0 + 1];
#pragma unroll
        for (int j = 0; j < 32; ++j) {
            const float xj = sm.m.r1[j * 32 + r];
            a0 = fmaf(sm.m.wsh[n0 * 32 + j],       xj, a0);
            a1 = fmaf(sm.m.wsh[(n0 + 1) * 32 + j], xj, a1);
        }
        sm.m.r2[n0 * 32 + r]       = fmaxf(a0, 0.0f);
        sm.m.r2[(n0 + 1) * 32 + r] = fmaxf(a1, 0.0f);
    }
    __syncthreads();

    // ---- layer 2 ----
    {
        const int r = tid & 31, n0 = (tid >> 5) * 2;
        float a0 = sm.m.wsh[2080 + n0];
        float a1 = sm.m.wsh[2080 + n0 + 1];
#pragma unroll
        for (int j = 0; j < 32; ++j) {
            const float xj = sm.m.r2[j * 32 + r];
            a0 = fmaf(sm.m.wsh[1024 + n0 * 32 + j],       xj, a0);
            a1 = fmaf(sm.m.wsh[1024 + (n0 + 1) * 32 + j], xj, a1);
        }
        sm.m.r1[n0 * 32 + r]       = fmaxf(a0, 0.0f);
        sm.m.r1[(n0 + 1) * 32 + r] = fmaxf(a1, 0.0f);
    }
    __syncthreads();

    // ---- last layer + store ----
    if (tid < M) {
        float res = sm.m.wsh[2144];
#pragma unroll
        for (int j = 0; j < 32; ++j)
            res = fmaf(sm.m.wsh[2112 + j], sm.m.r1[j * 32 + tid], res);
        out[row0 + tid] = res;
    }
}

} // namespace

extern "C" void kernel_launch(void* const* d_in, const int* in_sizes, int n_in,
                              void* d_out, int out_size, void* d_ws, size_t ws_size,
                              hipStream_t stream) {
    (void)in_sizes; (void)n_in; (void)out_size; (void)d_ws; (void)ws_size;
    const int*   Xi      = (const int*)d_in[0];
    const float* Xv      = (const float*)d_in[1];
    const float* T       = (const float*)d_in[2];
    const float* w_first = (const float*)d_in[3];
    const float* w_inner = (const float*)d_in[4];
    const float* lin1_W  = (const float*)d_in[5];
    const float* lin1_b  = (const float*)d_in[6];
    const float* lin2_W  = (const float*)d_in[7];
    const float* lin2_b  = (const float*)d_in[8];
    const float* last_W  = (const float*)d_in[9];
    const float* last_b  = (const float*)d_in[10];
    float* out = (float*)d_out;

    hipLaunchKernelGGL(pnn_fused, dim3(Bn / M), dim3(512), 0, stream,
                       Xi, Xv, T, w_first, w_inner,
                       lin1_W, lin1_b, lin2_W, lin2_b, last_W, last_b, out);
}